// Round 6
// baseline (773.670 us; speedup 1.0000x reference)
//
#include <hip/hip_runtime.h>
#include <hip/hip_bf16.h>
#include <cstdint>
#include <cstddef>

typedef __attribute__((ext_vector_type(4))) float f32x4;
typedef __attribute__((ext_vector_type(8))) short short8;
typedef unsigned short ushort_t;

// ---- helpers ---------------------------------------------------------------
__device__ __forceinline__ ushort_t f2bf(float f) {
  unsigned u = __builtin_bit_cast(unsigned, f);
  u = u + 0x7FFFu + ((u >> 16) & 1u);          // round-to-nearest-even
  return (ushort_t)(u >> 16);
}
__device__ __forceinline__ void load_lds16(const void* g, void* l) {
  __builtin_amdgcn_global_load_lds((const __attribute__((address_space(1))) void*)g,
                                   (__attribute__((address_space(3))) void*)l, 16, 0, 0);
}

// LDS byte-offset swizzles (applied identically on write and read)
__device__ __forceinline__ int swzQ(int row, int b) { return row*64  + (b ^ (((row >> 1) & 3) << 4)); } // 64B rows
__device__ __forceinline__ int swzV5(int d,  int b) { return d*512   + (b ^ ((d & 7) << 4)); }          // 512B rows

// ---- kernel 1: hidden f32 -> bf16 ------------------------------------------
__global__ __launch_bounds__(256) void k_cvt_bf16(const float4* __restrict__ in,
                                                  ushort_t* __restrict__ outp, int n4) {
  int i = blockIdx.x * 256 + threadIdx.x;
  int stride = gridDim.x * 256;
  for (; i < n4; i += stride) {
    float4 v = in[i];
    ushort4 o = { f2bf(v.x), f2bf(v.y), f2bf(v.z), f2bf(v.w) };
    *(ushort4*)(outp + (size_t)i * 4) = o;
  }
}

// ---- kernel 2: build head-grouped Wcat (bf16) + bcat (f32) -----------------
// Row order per head h: [q rows h*32..+32 | k rows | v rows]  (1536 rows of K=512)
__global__ __launch_bounds__(256) void k_wcat(const float* __restrict__ qw, const float* __restrict__ qb,
                                              const float* __restrict__ kw, const float* __restrict__ vw,
                                              const float* __restrict__ vb,
                                              ushort_t* __restrict__ Wcat, float* __restrict__ bcat) {
  int o = blockIdx.x;                   // 0..1535
  int h = o / 96, r = o % 96;
  const float* src; float bias;
  if (r < 32)      { src = qw + (size_t)(h*32 + r)      * 512; bias = qb[h*32 + r]; }
  else if (r < 64) { src = kw + (size_t)(h*32 + r - 32) * 512; bias = 0.f; }
  else             { src = vw + (size_t)(h*32 + r - 64) * 512; bias = vb[h*32 + r - 64]; }
  int t = threadIdx.x;
  Wcat[(size_t)o*512 + t]       = f2bf(src[t]);
  Wcat[(size_t)o*512 + t + 256] = f2bf(src[t + 256]);
  if (t == 0) bcat[o] = bias;
}

// ---- kernel 3: CPB MLP -> bias16[t][h] = 16*sigmoid(hbias) -----------------
__global__ __launch_bounds__(256) void k_bias(const float* __restrict__ w1, const float* __restrict__ b1,
                                              const float* __restrict__ w2, float* __restrict__ bias16) {
  int t = blockIdx.x;                   // 0..224 table rows
  int a = t / 15, b = t % 15;
  float x = (float)(a - 7) * (8.f / 7.f);
  float y = (float)(b - 7) * (8.f / 7.f);
  float fx = (x == 0.f) ? 0.f : copysignf(log2f(fabsf(x) + 1.f) * (1.f / 3.f), x);
  float fy = (y == 0.f) ? 0.f : copysignf(log2f(fabsf(y) + 1.f) * (1.f / 3.f), y);
  int wv = threadIdx.x >> 6, lane = threadIdx.x & 63;
  float acc[4] = {0.f, 0.f, 0.f, 0.f};
  for (int it = 0; it < 8; ++it) {
    int j = it*64 + lane;
    float act = fmaxf(fx * w1[2*j] + fy * w1[2*j + 1] + b1[j], 0.f);
#pragma unroll
    for (int hh = 0; hh < 4; ++hh)
      acc[hh] += act * w2[(wv*4 + hh)*512 + j];
  }
#pragma unroll
  for (int hh = 0; hh < 4; ++hh) {
    float v = acc[hh];
    for (int s = 1; s < 64; s <<= 1) v += __shfl_xor(v, s);
    if (lane == 0) bias16[t*16 + wv*4 + hh] = 16.f / (1.f + __expf(-v));
  }
}

// ---- kernel 4: fused QKV projection + cosine window attention --------------
// block = (mtile, head): 256 rows (= windows 4m..4m+3) x 96 cols (q|k|v of head h)
// 8 waves; GEMM wave w owns rows w*32..+32 (x all 96 cols).
// GEMM phase (BK=32, double-buffered, counted-vmcnt pipeline):
//   A buf0 [256][32] @0 (16K, swzQ), A buf1 @16K; B buf0 [96][32] @32K (6K), B buf1 @38912
// attn phase (aliases, after final barrier): wave w = (window w>>1, rows (w&1)*32..+32)
//   qs [256][32] @0 (16K, swzQ), ks [256][32] @16K (16K, swzQ),
//   vt [32][256] @32K (16K, swzV5, V transposed)
//   P scratch: per-wave 1K sub-slot aliasing its OWN already-read qs rows.
#define ABUF(bsel) ((bsel)*16384)
#define BBUF(bsel) (32768 + (bsel)*6144)
#define KS_OFF 16384
#define VT_OFF 32768

__global__ __launch_bounds__(512, 6) void k_main(const ushort_t* __restrict__ hbf,
                                                 const ushort_t* __restrict__ Wcat,
                                                 const float* __restrict__ bcat,
                                                 const float* __restrict__ bias16,
                                                 const float* __restrict__ lscale,
                                                 float* __restrict__ out) {
  __shared__ __align__(128) char lb_raw[49152];
  char* lb = lb_raw;

  int bid = blockIdx.x;
  int wg = (bid & 7) * 1024 + (bid >> 3);      // bijective XCD swizzle (8192 % 8 == 0)
  int mtile = wg >> 4;                         // 0..511
  int h     = wg & 15;

  int tid = threadIdx.x;
  int w = tid >> 6, lane = tid & 63;
  int lm = lane & 15, lg = lane >> 4;

  const ushort_t* Ag = hbf  + (size_t)mtile * 256 * 512;
  const ushort_t* Wg = Wcat + (size_t)h * 96 * 512;

  // staging source offsets (elements), inverse-swizzled for swzQ 64B rows:
  // dest = base + tid*16 -> row = tid>>2 (+128 for 2nd A chunk), slot = tid&3.
  int rA0 = tid >> 2, rA1 = 128 + (tid >> 2);
  int sl  = tid & 3;
  int offA0 = rA0*512 + (sl ^ ((rA0 >> 1) & 3))*8;   // also serves B (rows 0..95)
  int offA1 = rA1*512 + (sl ^ ((rA1 >> 1) & 3))*8;

  f32x4 acc[2][6] = {};

#define STAGE(ksn, bsel) do {                                                  \
    int kk0 = (ksn) * 32;                                                      \
    load_lds16(Ag + offA0 + kk0, lb + ABUF(bsel) + tid*16);                    \
    load_lds16(Ag + offA1 + kk0, lb + ABUF(bsel) + 8192 + tid*16);             \
    if (tid < 384)                                                             \
      load_lds16(Wg + offA0 + kk0, lb + BBUF(bsel) + tid*16);                  \
  } while (0)

  // ---- GEMM: 256x96 += A(256x512) * Wg^T, BK=32, 2-deep counted pipeline ---
  STAGE(0, 0);
#pragma unroll
  for (int ks = 0; ks < 16; ++ks) {
    int cur = ks & 1;
    if (ks < 15) {
      STAGE(ks + 1, cur ^ 1);
      // drain stage(ks) only; stage(ks+1) stays in flight (counted, never 0)
      if (tid < 384) asm volatile("s_waitcnt vmcnt(3)" ::: "memory");
      else           asm volatile("s_waitcnt vmcnt(2)" ::: "memory");
    } else {
      asm volatile("s_waitcnt vmcnt(0)" ::: "memory");
    }
    asm volatile("s_barrier" ::: "memory");    // raw: no compiler vmcnt(0) drain

    const char* Ab = lb + ABUF(cur);
    const char* Bb = lb + BBUF(cur);
    short8 av0 = *(const short8*)(Ab + swzQ(w*32      + lm, lg*16));
    short8 av1 = *(const short8*)(Ab + swzQ(w*32 + 16 + lm, lg*16));
    short8 bv[6];
#pragma unroll
    for (int j = 0; j < 6; ++j)
      bv[j] = *(const short8*)(Bb + swzQ(j*16 + lm, lg*16));
#pragma unroll
    for (int j = 0; j < 6; ++j)
      acc[0][j] = __builtin_amdgcn_mfma_f32_16x16x32_bf16(av0, bv[j], acc[0][j], 0, 0, 0);
#pragma unroll
    for (int j = 0; j < 6; ++j)
      acc[1][j] = __builtin_amdgcn_mfma_f32_16x16x32_bf16(av1, bv[j], acc[1][j], 0, 0, 0);

    asm volatile("s_barrier" ::: "memory");    // compute(ks) done before buf reuse
  }
#undef STAGE

  // ---- epilogue: bias + in-register normalize + write qs/ks/vt -------------
  __builtin_amdgcn_s_setprio(1);
  float scl = __expf(fminf(lscale[h], 4.6051701860f));   // exp(min(ls, ln 100))
  float bb[6];
#pragma unroll
  for (int nj = 0; nj < 6; ++nj) bb[nj] = bcat[h*96 + nj*16 + lm];

#pragma unroll
  for (int i = 0; i < 2; ++i) {
#pragma unroll
    for (int r = 0; r < 4; ++r) {
      float q0 = acc[i][0][r] + bb[0], q1 = acc[i][1][r] + bb[1];
      float k0 = acc[i][2][r],         k1 = acc[i][3][r];
      float ssq = q0*q0 + q1*q1;
      float ssk = k0*k0 + k1*k1;
      ssq += __shfl_xor(ssq, 1); ssq += __shfl_xor(ssq, 2);
      ssq += __shfl_xor(ssq, 4); ssq += __shfl_xor(ssq, 8);
      ssk += __shfl_xor(ssk, 1); ssk += __shfl_xor(ssk, 2);
      ssk += __shfl_xor(ssk, 4); ssk += __shfl_xor(ssk, 8);
      float rq = rsqrtf(ssq) * scl;     // fold logit scale into qn
      float rk = rsqrtf(ssk);
      int row = w*32 + i*16 + lg*4 + r;
      *(ushort_t*)(lb + swzQ(row, lm*2))               = f2bf(q0 * rq);
      *(ushort_t*)(lb + swzQ(row, 32 + lm*2))          = f2bf(q1 * rq);
      *(ushort_t*)(lb + KS_OFF + swzQ(row, lm*2))      = f2bf(k0 * rk);
      *(ushort_t*)(lb + KS_OFF + swzQ(row, 32 + lm*2)) = f2bf(k1 * rk);
    }
    // V^T: 4 consecutive tokens -> one swizzled b64 store
#pragma unroll
    for (int j = 0; j < 2; ++j) {
      ushort4 pk;
      pk.x = f2bf(acc[i][4+j][0] + bb[4+j]);
      pk.y = f2bf(acc[i][4+j][1] + bb[4+j]);
      pk.z = f2bf(acc[i][4+j][2] + bb[4+j]);
      pk.w = f2bf(acc[i][4+j][3] + bb[4+j]);
      int d = j*16 + lm, tokb = (w*32 + i*16 + lg*4) * 2;
      *(ushort4*)(lb + VT_OFF + swzV5(d, tokb)) = pk;
    }
  }
  __syncthreads();

  // ---- attention: wave w owns window w>>1, rows (w&1)*32..+32 (its own GEMM
  //      rows) — q read wave-private, P scratch aliases own dead qs rows ------
  int win = w >> 1;
  int nb  = (w & 1) * 32;
#pragma unroll
  for (int mi = 0; mi < 2; ++mi) {
    short8 aq = *(const short8*)(lb + swzQ(w*32 + mi*16 + lm, lg*16));
    f32x4 s4[4];
#pragma unroll
    for (int ci = 0; ci < 4; ++ci) {
      short8 bk = *(const short8*)(lb + KS_OFF + swzQ(win*64 + ci*16 + lm, lg*16));
      f32x4 z = {0.f, 0.f, 0.f, 0.f};
      s4[ci] = __builtin_amdgcn_mfma_f32_16x16x32_bf16(aq, bk, z, 0, 0, 0);
    }
    // bias (L1-hot 14.4 KB table) + exp; no max-sub: |arg| <= 26, f32-safe
#pragma unroll
    for (int ci = 0; ci < 4; ++ci) {
      int m = ci*16 + lm, rm = m >> 3, cm = m & 7;
#pragma unroll
      for (int r = 0; r < 4; ++r) {
        int n = nb + mi*16 + lg*4 + r;
        int idx = ((n >> 3) - rm + 7)*15 + ((n & 7) - cm + 7);
        s4[ci][r] = __expf(s4[ci][r] + bias16[idx*16 + h]);
      }
    }
    float rs[4];
#pragma unroll
    for (int r = 0; r < 4; ++r) {
      float s = s4[0][r] + s4[1][r] + s4[2][r] + s4[3][r];
      s += __shfl_xor(s, 1); s += __shfl_xor(s, 2);
      s += __shfl_xor(s, 4); s += __shfl_xor(s, 8);
      rs[r] = 1.f / s;
    }
    // PV in 2 half-K steps through the wave's own 1K qs sub-slot (in-order DS)
    char* slot = lb + w*2048 + mi*1024;
    f32x4 oacc[2] = {};
#pragma unroll
    for (int kk = 0; kk < 2; ++kk) {
#pragma unroll
      for (int cc = 0; cc < 2; ++cc) {
        int ci = kk*2 + cc;
#pragma unroll
        for (int r = 0; r < 4; ++r) {
          int pr = lg*4 + r;
          *(ushort_t*)(slot + swzQ(pr, cc*32 + lm*2)) = f2bf(s4[ci][r]);
        }
      }
      short8 ap = *(const short8*)(slot + swzQ(lm, lg*16));
#pragma unroll
      for (int c2 = 0; c2 < 2; ++c2) {
        short8 bvv = *(const short8*)(lb + VT_OFF + swzV5(c2*16 + lm, win*128 + kk*64 + lg*16));
        oacc[c2] = __builtin_amdgcn_mfma_f32_16x16x32_bf16(ap, bvv, oacc[c2], 0, 0, 0);
      }
    }
    size_t rowb = (size_t)mtile*256 + w*32 + mi*16;
#pragma unroll
    for (int c2 = 0; c2 < 2; ++c2)
#pragma unroll
      for (int r = 0; r < 4; ++r)
        out[(rowb + lg*4 + r)*512 + h*32 + c2*16 + lm] = oacc[c2][r] * rs[r];
  }
  __builtin_amdgcn_s_setprio(0);
}

// ---- launcher ---------------------------------------------------------------
extern "C" void kernel_launch(void* const* d_in, const int* in_sizes, int n_in,
                              void* d_out, int out_size, void* d_ws, size_t ws_size,
                              hipStream_t stream) {
  (void)in_sizes; (void)n_in; (void)out_size; (void)ws_size;
  const float* hidden = (const float*)d_in[0];
  const float* q_w    = (const float*)d_in[1];
  const float* q_b    = (const float*)d_in[2];
  const float* k_w    = (const float*)d_in[3];
  const float* v_w    = (const float*)d_in[4];
  const float* v_b    = (const float*)d_in[5];
  const float* lscale = (const float*)d_in[6];
  const float* cpb_w1 = (const float*)d_in[7];
  const float* cpb_b1 = (const float*)d_in[8];
  const float* cpb_w2 = (const float*)d_in[9];
  float* out = (float*)d_out;

  char* wsb = (char*)d_ws;
  ushort_t* hbf    = (ushort_t*)wsb;                        // 134,217,728 B
  ushort_t* Wcat   = (ushort_t*)(wsb + 134217728);          //   1,572,864 B
  float*    bcat   = (float*)(wsb + 135790592);             //       6,144 B
  float*    bias16 = (float*)(wsb + 135796736);             //      14,400 B

  hipLaunchKernelGGL(k_cvt_bf16, dim3(2048), dim3(256), 0, stream,
                     (const float4*)hidden, hbf, 16777216);
  hipLaunchKernelGGL(k_wcat, dim3(1536), dim3(256), 0, stream,
                     q_w, q_b, k_w, v_w, v_b, Wcat, bcat);
  hipLaunchKernelGGL(k_bias, dim3(225), dim3(256), 0, stream,
                     cpb_w1, cpb_b1, cpb_w2, bias16);
  hipLaunchKernelGGL(k_main, dim3(8192), dim3(512), 0, stream,
                     hbf, Wcat, bcat, bias16, lscale, out);
}